// Round 1
// baseline (325.207 us; speedup 1.0000x reference)
//
#include <hip/hip_runtime.h>
#include <stdint.h>

// B=512, T=256, N_EMBED=384, HEAD_SIZE=64
// Single fused kernel per batch (prep_w folded in; d_ws UNUSED on purpose:
// the harness's 768 MiB workspace poison-fill dominated the timed region).
// Phase 1: kc-outer QKV projection, double-buffered LDS staging (ONE barrier
//          per kc), 2-deep x register prefetch, W gathered fp32->bf16 in-kernel
//          (identical index math + f2bf as the old prep_w => bit-identical).
// Phase 2: causal flash attention, unchanged from the 317 us version.
// LDS total = 163840 B: Kf 32K + Qf 32K + Vf 32K + P 64K
//             (P region aliases phase-1 staging dbuf: 2 x (Xc 16K + Wsl 12K)).

typedef short s16x8 __attribute__((ext_vector_type(8)));
typedef short s16x4 __attribute__((ext_vector_type(4)));
typedef float f32x4 __attribute__((ext_vector_type(4)));

#define LOG2E_OVER_8 0.18033688011112042f

__device__ inline short f2bf(float f) {
  union { float f; uint32_t u; } v; v.f = f;
  uint32_t r = (v.u + 0x7fffu + ((v.u >> 16) & 1u)) >> 16;  // RNE
  return (short)r;
}

__global__ __launch_bounds__(1024) void fused_head(const float* __restrict__ x,
                                                   const float* __restrict__ Wk,
                                                   const float* __restrict__ Wq,
                                                   const float* __restrict__ Wv,
                                                   float* __restrict__ out) {
  __shared__ __align__(16) short LDS[81920];  // 163840 B
  short* Kf = LDS;            // [stile16*2+frag][lane*8+j]  (B-frag: n=s, k=h)
  short* Qf = LDS + 16384;    // [qtile16*2+frag][lane*8+j]  (A-frag: m=q, k=h)
  short* Vf = LDS + 32768;    // [sblk32*4+htile][lane*8+j]  (B-frag: n=h, k=s)
  short* Pb = LDS + 49152;    // phase 2: 16 waves x 2048 shorts (A-frag)
                              // phase 1 alias: staging dbuf, stride 14336 shorts

  const int tid = threadIdx.x;
  const int wave = tid >> 6;
  const int lane = tid & 63;
  const int l15 = lane & 15;
  const int quad = lane >> 4;
  const int b = blockIdx.x;
  const float* xb = x + (long)b * (256 * 384);

  // ======== Phase 1: QKV projection (kc-outer, dbuf staging) ========
  const int mgrp = wave >> 2;  // 4 m-tiles (64 rows)
  const int ngrp = wave & 3;   // 3 n-tiles (48 cols)

  // x staging: slot = tid + j*1024; m=slot>>3, kq=(slot&7)*4
  const int m0s = tid >> 3;
  const int kq0 = (tid & 7) * 4;
  const int xoff0 = m0s * 384 + kq0;
  const int xoff1 = xoff0 + 128 * 384;
  const int lds0 = (m0s >> 4) * 512 + ((m0s & 15) + (kq0 >> 3) * 16) * 8 + (kq0 & 7);
  const int lds1 = lds0 + 8 * 512;
  const bool wact = (tid < 768);

  // W gather (replaces prep_w): thread tid<768 owns frag slot [ntile][lane][0..7]
  // ntile 0..3 = K, 4..7 = Q (prescaled by 0.125*log2e), 8..11 = V
  const int wntile = tid >> 6;              // == wave, 0..11 active
  const int wn = wntile * 16 + l15;
  const int wcol = wn & 63;
  const int ww = wn >> 6;                   // 0=K 1=Q 2=V
  const float* Wsel = (ww == 0) ? Wk : (ww == 1) ? Wq : Wv;
  const float wscale = (ww == 1) ? LOG2E_OVER_8 : 1.0f;
  const int wbase = (lane >> 4) * 8 * 64 + wcol;  // + kc*2048 + j*64

  f32x4 acc[4][3];
#pragma unroll
  for (int i = 0; i < 4; ++i)
#pragma unroll
    for (int k2 = 0; k2 < 3; ++k2) acc[i][k2] = (f32x4)0.0f;

  // 2-deep x prefetch: A holds even kc, B holds odd kc. W is 1-deep (L2-hot).
  f32x4 xA0 = *(const f32x4*)(xb + xoff0);
  f32x4 xA1 = *(const f32x4*)(xb + xoff1);
  f32x4 xB0 = *(const f32x4*)(xb + xoff0 + 32);
  f32x4 xB1 = *(const f32x4*)(xb + xoff1 + 32);
  float wf[8];
  if (wact) {
#pragma unroll
    for (int j = 0; j < 8; ++j) wf[j] = Wsel[wbase + j * 64];
  }

#pragma unroll
  for (int kc = 0; kc < 12; ++kc) {
    short* XcS = LDS + 49152 + (kc & 1) * 14336;  // staging x slice (8192 shorts)
    short* WslS = XcS + 8192;                     // staging W slice (6144 shorts)

    // stage current kc (convert to bf16). (kc&1) is compile-time (full unroll).
    {
      const f32x4 cx0 = (kc & 1) ? xB0 : xA0;
      const f32x4 cx1 = (kc & 1) ? xB1 : xA1;
      s16x4 h0, h1;
      h0[0] = f2bf(cx0[0]); h0[1] = f2bf(cx0[1]); h0[2] = f2bf(cx0[2]); h0[3] = f2bf(cx0[3]);
      h1[0] = f2bf(cx1[0]); h1[1] = f2bf(cx1[1]); h1[2] = f2bf(cx1[2]); h1[3] = f2bf(cx1[3]);
      *(s16x4*)(XcS + lds0) = h0;
      *(s16x4*)(XcS + lds1) = h1;
    }
    if (wact) {
      s16x8 wv8;
#pragma unroll
      for (int j = 0; j < 8; ++j) wv8[j] = f2bf(wf[j] * wscale);
      *(s16x8*)(WslS + tid * 8) = wv8;
    }

    __syncthreads();  // the ONLY barrier per kc (dbuf: writes hit the other
                      // buffer; reads 2 iters back are lgkm-drained by barriers)

    // prefetch x for kc+2 into the just-consumed parity buffer, W for kc+1.
    // Issued here so they stay in flight across ~2 iterations (~>900 cyc).
    if (kc + 2 < 12) {
      if (kc & 1) {
        xB0 = *(const f32x4*)(xb + xoff0 + (kc + 2) * 32);
        xB1 = *(const f32x4*)(xb + xoff1 + (kc + 2) * 32);
      } else {
        xA0 = *(const f32x4*)(xb + xoff0 + (kc + 2) * 32);
        xA1 = *(const f32x4*)(xb + xoff1 + (kc + 2) * 32);
      }
    }
    if (wact && (kc + 1 < 12)) {
#pragma unroll
      for (int j = 0; j < 8; ++j) wf[j] = Wsel[(kc + 1) * 2048 + wbase + j * 64];
    }

    s16x8 af[4];
#pragma unroll
    for (int i = 0; i < 4; ++i)
      af[i] = *(const s16x8*)(XcS + (mgrp * 4 + i) * 512 + lane * 8);
#pragma unroll
    for (int k2 = 0; k2 < 3; ++k2) {
      s16x8 bfv = *(const s16x8*)(WslS + (ngrp * 3 + k2) * 512 + lane * 8);
#pragma unroll
      for (int i = 0; i < 4; ++i)
        acc[i][k2] = __builtin_amdgcn_mfma_f32_16x16x32_bf16(af[i], bfv, acc[i][k2], 0, 0, 0);
    }
  }

  // epilogue: C layout (row=quad*4+r, col=nt*16+l15) -> fragment-ordered K/Q/V
#pragma unroll
  for (int i = 0; i < 4; ++i) {
    const int rowb = (mgrp * 4 + i) * 16 + quad * 4;
#pragma unroll
    for (int k2 = 0; k2 < 3; ++k2) {
      const int nt = ngrp * 3 + k2;  // 0..11 (wave-uniform)
      const int h = (nt * 16 + l15) & 63;
      const int which = nt >> 2;
#pragma unroll
      for (int r = 0; r < 4; ++r) {
        const short v = f2bf(acc[i][k2][r]);
        const int row = rowb + r;
        if (which == 0)
          Kf[((row >> 4) * 2 + (h >> 5)) * 512 + ((row & 15) + ((h & 31) >> 3) * 16) * 8 + (h & 7)] = v;
        else if (which == 1)
          Qf[((row >> 4) * 2 + (h >> 5)) * 512 + ((row & 15) + ((h & 31) >> 3) * 16) * 8 + (h & 7)] = v;
        else
          Vf[((row >> 5) * 4 + (h >> 4)) * 512 + ((h & 15) + ((row & 31) >> 3) * 16) * 8 + (row & 7)] = v;
      }
    }
  }
  __syncthreads();  // K/Q/V complete; staging area (P region) free

  // ======== Phase 2: causal attention, wave w owns q-subtile w ========
  const int t = wave;
  const int q0 = t * 16;
  short* Pw = Pb + wave * 2048;

  s16x8 qf0 = *(const s16x8*)(Qf + (t * 2 + 0) * 512 + lane * 8);
  s16x8 qf1 = *(const s16x8*)(Qf + (t * 2 + 1) * 512 + lane * 8);

  f32x4 Oacc[4];
#pragma unroll
  for (int n = 0; n < 4; ++n) Oacc[n] = (f32x4)0.0f;
  float mrow[4] = {-1e30f, -1e30f, -1e30f, -1e30f};
  float lrow[4] = {0.f, 0.f, 0.f, 0.f};

  const int nb = (t >= 8) ? 2 : 1;
  for (int cb = 0; cb < nb; ++cb) {
    const int st0 = cb * 8;                       // first 16-s-tile of this 128-chunk
    const bool last = (cb == nb - 1);
    const int nuse = last ? (t - cb * 8 + 1) : 8; // tiles with any unmasked col

    float S[8][4];
#pragma unroll
    for (int n = 0; n < 8; ++n) {
      if (n < nuse) {
        s16x8 kf0 = *(const s16x8*)(Kf + ((st0 + n) * 2 + 0) * 512 + lane * 8);
        s16x8 kf1 = *(const s16x8*)(Kf + ((st0 + n) * 2 + 1) * 512 + lane * 8);
        f32x4 z = (f32x4)0.0f;
        z = __builtin_amdgcn_mfma_f32_16x16x32_bf16(qf0, kf0, z, 0, 0, 0);
        z = __builtin_amdgcn_mfma_f32_16x16x32_bf16(qf1, kf1, z, 0, 0, 0);
        if (last) {
          const int s_abs = cb * 128 + n * 16 + l15;
#pragma unroll
          for (int r = 0; r < 4; ++r) {
            const int q_abs = q0 + quad * 4 + r;
            S[n][r] = (s_abs > q_abs) ? -1e30f : z[r];
          }
        } else {
#pragma unroll
          for (int r = 0; r < 4; ++r) S[n][r] = z[r];
        }
      } else {
#pragma unroll
        for (int r = 0; r < 4; ++r) S[n][r] = -1e30f;
      }
    }

    // online softmax (base-2); row r lives in the 16 lanes of this quad
    float alpha[4];
#pragma unroll
    for (int r = 0; r < 4; ++r) {
      float mx = S[0][r];
#pragma unroll
      for (int n = 1; n < 8; ++n) mx = fmaxf(mx, S[n][r]);
      mx = fmaxf(mx, __shfl_xor(mx, 1));
      mx = fmaxf(mx, __shfl_xor(mx, 2));
      mx = fmaxf(mx, __shfl_xor(mx, 4));
      mx = fmaxf(mx, __shfl_xor(mx, 8));
      float mnew = fmaxf(mrow[r], mx);
      alpha[r] = __builtin_amdgcn_exp2f(mrow[r] - mnew);
      mrow[r] = mnew;
    }
    float rs[4] = {0.f, 0.f, 0.f, 0.f};
#pragma unroll
    for (int n = 0; n < 8; ++n) {
#pragma unroll
      for (int r = 0; r < 4; ++r) {
        float p = __builtin_amdgcn_exp2f(S[n][r] - mrow[r]);  // masked -> 0
        rs[r] += p;
        Pw[(n >> 1) * 512 + ((quad * 4 + r) + ((n & 1) * 2 + (l15 >> 3)) * 16) * 8 + (l15 & 7)] = f2bf(p);
      }
    }
#pragma unroll
    for (int r = 0; r < 4; ++r) {
      float s = rs[r];
      s += __shfl_xor(s, 1);
      s += __shfl_xor(s, 2);
      s += __shfl_xor(s, 4);
      s += __shfl_xor(s, 8);
      lrow[r] = lrow[r] * alpha[r] + s;
#pragma unroll
      for (int n = 0; n < 4; ++n) Oacc[n][r] *= alpha[r];
    }
    // P strip is wave-private: drain DS writes before re-reading (no barrier)
    asm volatile("s_waitcnt lgkmcnt(0)" ::: "memory");

    // O += P V over the live 32-s blocks
    const int kblks = (nuse + 1) >> 1;
    for (int sb = 0; sb < kblks; ++sb) {
      s16x8 pf = *(const s16x8*)(Pw + sb * 512 + lane * 8);
#pragma unroll
      for (int n2 = 0; n2 < 4; ++n2) {
        s16x8 vfv = *(const s16x8*)(Vf + ((cb * 4 + sb) * 4 + n2) * 512 + lane * 8);
        Oacc[n2] = __builtin_amdgcn_mfma_f32_16x16x32_bf16(pf, vfv, Oacc[n2], 0, 0, 0);
      }
    }
  }

  float inv[4];
#pragma unroll
  for (int r = 0; r < 4; ++r) inv[r] = 1.0f / lrow[r];
  float* ob = out + ((long)b * 256 + q0 + quad * 4) * 64;
#pragma unroll
  for (int n = 0; n < 4; ++n)
#pragma unroll
    for (int r = 0; r < 4; ++r)
      ob[r * 64 + n * 16 + l15] = Oacc[n][r] * inv[r];
}

extern "C" void kernel_launch(void* const* d_in, const int* in_sizes, int n_in,
                              void* d_out, int out_size, void* d_ws, size_t ws_size,
                              hipStream_t stream) {
  const float* x = (const float*)d_in[0];
  const float* Wk = (const float*)d_in[1];
  const float* Wq = (const float*)d_in[2];
  const float* Wv = (const float*)d_in[3];
  float* out = (float*)d_out;
  (void)d_ws; (void)ws_size;  // workspace deliberately unused (poison-fill cost)
  fused_head<<<512, 1024, 0, stream>>>(x, Wk, Wq, Wv, out);
}

// Round 2
// 317.572 us; speedup vs baseline: 1.0240x; 1.0240x over previous
//
#include <hip/hip_runtime.h>
#include <stdint.h>

// B=512, T=256, N_EMBED=384, HEAD_SIZE=64
// One block per batch, 1024 threads (16 waves, 4/SIMD).
// Round-2 changes vs round 1:
//  - __launch_bounds__(1024, 4): LDS (160 KiB) already limits to 1 block/CU
//    (4 waves/SIMD), so the 64-VGPR cap from default launch_bounds only
//    caused scratch spills (S[8][4]+Oacc+acc all live). 128-VGPR budget.
//  - W path reverted to prep_w + bf16 fragment-ordered Wt3 in d_ws
//    (ws poison-fill is unconditional, so using d_ws is free; coalesced
//    16B/thread loads instead of 8x stride-256B fp32 gathers).
//  - Phase 1 keeps round-1 dbuf staging: ONE barrier per kc, 2-deep x
//    register prefetch.
// Phase 2: causal flash attention, unchanged.
// LDS total = 163840 B: Kf 32K + Qf 32K + Vf 32K + P 64K
//             (P region aliases phase-1 staging dbuf: 2 x (Xc 16K + Wsl 12K)).

typedef short s16x8 __attribute__((ext_vector_type(8)));
typedef short s16x4 __attribute__((ext_vector_type(4)));
typedef float f32x4 __attribute__((ext_vector_type(4)));

#define LOG2E_OVER_8 0.18033688011112042f

__device__ inline short f2bf(float f) {
  union { float f; uint32_t u; } v; v.f = f;
  uint32_t r = (v.u + 0x7fffu + ((v.u >> 16) & 1u)) >> 16;  // RNE
  return (short)r;
}

// ---- Kernel 0: W fp32 -> bf16 fragment-ordered Wt3, fold 0.125*log2e into Wq
__global__ __launch_bounds__(256) void prep_w(const float* __restrict__ Wk,
                                              const float* __restrict__ Wq,
                                              const float* __restrict__ Wv,
                                              short* __restrict__ Wt3) {
  int idx = blockIdx.x * 256 + threadIdx.x;  // 0..73727
  int j = idx & 7;
  int lane = (idx >> 3) & 63;
  int rest = idx >> 9;          // 0..143
  int ntile = rest % 12;
  int kc = rest / 12;
  int n = ntile * 16 + (lane & 15);
  int kk = (lane >> 4) * 8 + j;
  int col = n & 63;
  int w = n >> 6;
  const float* W = (w == 0) ? Wk : (w == 1) ? Wq : Wv;
  float v = W[(kc * 32 + kk) * 64 + col];
  if (w == 1) v *= LOG2E_OVER_8;
  Wt3[idx] = f2bf(v);
}

// ---- Fused kernel: one block per batch, 1024 threads.
__global__ __launch_bounds__(1024, 4) void fused_head(const float* __restrict__ x,
                                                      const short* __restrict__ Wt3,
                                                      float* __restrict__ out) {
  __shared__ __align__(16) short LDS[81920];  // 163840 B
  short* Kf = LDS;            // [stile16*2+frag][lane*8+j]  (B-frag: n=s, k=h)
  short* Qf = LDS + 16384;    // [qtile16*2+frag][lane*8+j]  (A-frag: m=q, k=h)
  short* Vf = LDS + 32768;    // [sblk32*4+htile][lane*8+j]  (B-frag: n=h, k=s)
  short* Pb = LDS + 49152;    // phase 2: 16 waves x 2048 shorts (A-frag)
                              // phase 1 alias: staging dbuf, stride 14336 shorts

  const int tid = threadIdx.x;
  const int wave = tid >> 6;
  const int lane = tid & 63;
  const int l15 = lane & 15;
  const int quad = lane >> 4;
  const int b = blockIdx.x;
  const float* xb = x + (long)b * (256 * 384);

  // ======== Phase 1: QKV projection (kc-outer, dbuf staging) ========
  const int mgrp = wave >> 2;  // 4 m-tiles (64 rows)
  const int ngrp = wave & 3;   // 3 n-tiles (48 cols)

  // x staging: slot = tid + j*1024; m=slot>>3, kq=(slot&7)*4
  const int m0s = tid >> 3;
  const int kq0 = (tid & 7) * 4;
  const int xoff0 = m0s * 384 + kq0;
  const int xoff1 = xoff0 + 128 * 384;
  const int lds0 = (m0s >> 4) * 512 + ((m0s & 15) + (kq0 >> 3) * 16) * 8 + (kq0 & 7);
  const int lds1 = lds0 + 8 * 512;
  const bool wact = (tid < 768);

  f32x4 acc[4][3];
#pragma unroll
  for (int i = 0; i < 4; ++i)
#pragma unroll
    for (int k2 = 0; k2 < 3; ++k2) acc[i][k2] = (f32x4)0.0f;

  // 2-deep x prefetch: A holds even kc, B holds odd kc. W is 1-deep (L2-hot).
  f32x4 xA0 = *(const f32x4*)(xb + xoff0);
  f32x4 xA1 = *(const f32x4*)(xb + xoff1);
  f32x4 xB0 = *(const f32x4*)(xb + xoff0 + 32);
  f32x4 xB1 = *(const f32x4*)(xb + xoff1 + 32);
  s16x8 wv;
  if (wact) wv = *(const s16x8*)(Wt3 + tid * 8);

#pragma unroll
  for (int kc = 0; kc < 12; ++kc) {
    short* XcS = LDS + 49152 + (kc & 1) * 14336;  // staging x slice (8192 shorts)
    short* WslS = XcS + 8192;                     // staging W slice (6144 shorts)

    // stage current kc (convert to bf16). (kc&1) is compile-time (full unroll).
    {
      const f32x4 cx0 = (kc & 1) ? xB0 : xA0;
      const f32x4 cx1 = (kc & 1) ? xB1 : xA1;
      s16x4 h0, h1;
      h0[0] = f2bf(cx0[0]); h0[1] = f2bf(cx0[1]); h0[2] = f2bf(cx0[2]); h0[3] = f2bf(cx0[3]);
      h1[0] = f2bf(cx1[0]); h1[1] = f2bf(cx1[1]); h1[2] = f2bf(cx1[2]); h1[3] = f2bf(cx1[3]);
      *(s16x4*)(XcS + lds0) = h0;
      *(s16x4*)(XcS + lds1) = h1;
    }
    if (wact) *(s16x8*)(WslS + tid * 8) = wv;

    __syncthreads();  // the ONLY barrier per kc (dbuf: writes hit the other
                      // buffer; reads 2 iters back are lgkm-drained by barriers)

    // prefetch x for kc+2 into the just-consumed parity buffer, W for kc+1.
    if (kc + 2 < 12) {
      if (kc & 1) {
        xB0 = *(const f32x4*)(xb + xoff0 + (kc + 2) * 32);
        xB1 = *(const f32x4*)(xb + xoff1 + (kc + 2) * 32);
      } else {
        xA0 = *(const f32x4*)(xb + xoff0 + (kc + 2) * 32);
        xA1 = *(const f32x4*)(xb + xoff1 + (kc + 2) * 32);
      }
    }
    if (wact && (kc + 1 < 12))
      wv = *(const s16x8*)(Wt3 + (kc + 1) * 6144 + tid * 8);

    s16x8 af[4];
#pragma unroll
    for (int i = 0; i < 4; ++i)
      af[i] = *(const s16x8*)(XcS + (mgrp * 4 + i) * 512 + lane * 8);
#pragma unroll
    for (int k2 = 0; k2 < 3; ++k2) {
      s16x8 bfv = *(const s16x8*)(WslS + (ngrp * 3 + k2) * 512 + lane * 8);
#pragma unroll
      for (int i = 0; i < 4; ++i)
        acc[i][k2] = __builtin_amdgcn_mfma_f32_16x16x32_bf16(af[i], bfv, acc[i][k2], 0, 0, 0);
    }
  }

  // epilogue: C layout (row=quad*4+r, col=nt*16+l15) -> fragment-ordered K/Q/V
#pragma unroll
  for (int i = 0; i < 4; ++i) {
    const int rowb = (mgrp * 4 + i) * 16 + quad * 4;
#pragma unroll
    for (int k2 = 0; k2 < 3; ++k2) {
      const int nt = ngrp * 3 + k2;  // 0..11 (wave-uniform)
      const int h = (nt * 16 + l15) & 63;
      const int which = nt >> 2;
#pragma unroll
      for (int r = 0; r < 4; ++r) {
        const short v = f2bf(acc[i][k2][r]);
        const int row = rowb + r;
        if (which == 0)
          Kf[((row >> 4) * 2 + (h >> 5)) * 512 + ((row & 15) + ((h & 31) >> 3) * 16) * 8 + (h & 7)] = v;
        else if (which == 1)
          Qf[((row >> 4) * 2 + (h >> 5)) * 512 + ((row & 15) + ((h & 31) >> 3) * 16) * 8 + (h & 7)] = v;
        else
          Vf[((row >> 5) * 4 + (h >> 4)) * 512 + ((h & 15) + ((row & 31) >> 3) * 16) * 8 + (row & 7)] = v;
      }
    }
  }
  __syncthreads();  // K/Q/V complete; staging area (P region) free

  // ======== Phase 2: causal attention, wave w owns q-subtile w ========
  const int t = wave;
  const int q0 = t * 16;
  short* Pw = Pb + wave * 2048;

  s16x8 qf0 = *(const s16x8*)(Qf + (t * 2 + 0) * 512 + lane * 8);
  s16x8 qf1 = *(const s16x8*)(Qf + (t * 2 + 1) * 512 + lane * 8);

  f32x4 Oacc[4];
#pragma unroll
  for (int n = 0; n < 4; ++n) Oacc[n] = (f32x4)0.0f;
  float mrow[4] = {-1e30f, -1e30f, -1e30f, -1e30f};
  float lrow[4] = {0.f, 0.f, 0.f, 0.f};

  const int nb = (t >= 8) ? 2 : 1;
  for (int cb = 0; cb < nb; ++cb) {
    const int st0 = cb * 8;                       // first 16-s-tile of this 128-chunk
    const bool last = (cb == nb - 1);
    const int nuse = last ? (t - cb * 8 + 1) : 8; // tiles with any unmasked col

    float S[8][4];
#pragma unroll
    for (int n = 0; n < 8; ++n) {
      if (n < nuse) {
        s16x8 kf0 = *(const s16x8*)(Kf + ((st0 + n) * 2 + 0) * 512 + lane * 8);
        s16x8 kf1 = *(const s16x8*)(Kf + ((st0 + n) * 2 + 1) * 512 + lane * 8);
        f32x4 z = (f32x4)0.0f;
        z = __builtin_amdgcn_mfma_f32_16x16x32_bf16(qf0, kf0, z, 0, 0, 0);
        z = __builtin_amdgcn_mfma_f32_16x16x32_bf16(qf1, kf1, z, 0, 0, 0);
        if (last) {
          const int s_abs = cb * 128 + n * 16 + l15;
#pragma unroll
          for (int r = 0; r < 4; ++r) {
            const int q_abs = q0 + quad * 4 + r;
            S[n][r] = (s_abs > q_abs) ? -1e30f : z[r];
          }
        } else {
#pragma unroll
          for (int r = 0; r < 4; ++r) S[n][r] = z[r];
        }
      } else {
#pragma unroll
        for (int r = 0; r < 4; ++r) S[n][r] = -1e30f;
      }
    }

    // online softmax (base-2); row r lives in the 16 lanes of this quad
    float alpha[4];
#pragma unroll
    for (int r = 0; r < 4; ++r) {
      float mx = S[0][r];
#pragma unroll
      for (int n = 1; n < 8; ++n) mx = fmaxf(mx, S[n][r]);
      mx = fmaxf(mx, __shfl_xor(mx, 1));
      mx = fmaxf(mx, __shfl_xor(mx, 2));
      mx = fmaxf(mx, __shfl_xor(mx, 4));
      mx = fmaxf(mx, __shfl_xor(mx, 8));
      float mnew = fmaxf(mrow[r], mx);
      alpha[r] = __builtin_amdgcn_exp2f(mrow[r] - mnew);
      mrow[r] = mnew;
    }
    float rs[4] = {0.f, 0.f, 0.f, 0.f};
#pragma unroll
    for (int n = 0; n < 8; ++n) {
#pragma unroll
      for (int r = 0; r < 4; ++r) {
        float p = __builtin_amdgcn_exp2f(S[n][r] - mrow[r]);  // masked -> 0
        rs[r] += p;
        Pw[(n >> 1) * 512 + ((quad * 4 + r) + ((n & 1) * 2 + (l15 >> 3)) * 16) * 8 + (l15 & 7)] = f2bf(p);
      }
    }
#pragma unroll
    for (int r = 0; r < 4; ++r) {
      float s = rs[r];
      s += __shfl_xor(s, 1);
      s += __shfl_xor(s, 2);
      s += __shfl_xor(s, 4);
      s += __shfl_xor(s, 8);
      lrow[r] = lrow[r] * alpha[r] + s;
#pragma unroll
      for (int n = 0; n < 4; ++n) Oacc[n][r] *= alpha[r];
    }
    // P strip is wave-private: drain DS writes before re-reading (no barrier)
    asm volatile("s_waitcnt lgkmcnt(0)" ::: "memory");

    // O += P V over the live 32-s blocks
    const int kblks = (nuse + 1) >> 1;
    for (int sb = 0; sb < kblks; ++sb) {
      s16x8 pf = *(const s16x8*)(Pw + sb * 512 + lane * 8);
#pragma unroll
      for (int n2 = 0; n2 < 4; ++n2) {
        s16x8 vfv = *(const s16x8*)(Vf + ((cb * 4 + sb) * 4 + n2) * 512 + lane * 8);
        Oacc[n2] = __builtin_amdgcn_mfma_f32_16x16x32_bf16(pf, vfv, Oacc[n2], 0, 0, 0);
      }
    }
  }

  float inv[4];
#pragma unroll
  for (int r = 0; r < 4; ++r) inv[r] = 1.0f / lrow[r];
  float* ob = out + ((long)b * 256 + q0 + quad * 4) * 64;
#pragma unroll
  for (int n = 0; n < 4; ++n)
#pragma unroll
    for (int r = 0; r < 4; ++r)
      ob[r * 64 + n * 16 + l15] = Oacc[n][r] * inv[r];
}

extern "C" void kernel_launch(void* const* d_in, const int* in_sizes, int n_in,
                              void* d_out, int out_size, void* d_ws, size_t ws_size,
                              hipStream_t stream) {
  const float* x = (const float*)d_in[0];
  const float* Wk = (const float*)d_in[1];
  const float* Wq = (const float*)d_in[2];
  const float* Wv = (const float*)d_in[3];
  float* out = (float*)d_out;
  short* Wt3 = (short*)d_ws;  // 147456 B

  prep_w<<<288, 256, 0, stream>>>(Wk, Wq, Wv, Wt3);
  fused_head<<<512, 1024, 0, stream>>>(x, Wt3, out);
}